// Round 1
// baseline (12.718 us; speedup 1.0000x reference)
//
#include <hip/hip_runtime.h>

#define AE_EPS 1e-6f

// Problem-structure constants (from reference setup_inputs):
//   B=32 images, P=30 persons, K=17 keypoints, D=4 tag dims, N=17*128*128.
// B and N are derived from sizes at launch; P/K/D are structural.
constexpr int AE_P = 30;
constexpr int AE_K = 17;
constexpr int AE_D = 4;

__global__ __launch_bounds__(64)
void aeloss_kernel(const float* __restrict__ tags,
                   const int*  __restrict__ kps,
                   float* __restrict__ out,
                   int N)
{
    const int b   = blockIdx.x;
    const int tid = threadIdx.x;

    __shared__ float t_lds[AE_P][AE_K][AE_D];   // gathered tags
    __shared__ float m_lds[AE_P][AE_K];         // visibility mask (0/1)
    __shared__ float mean_lds[AE_P][AE_D];
    __shared__ float pull_lds[AE_P];
    __shared__ float valid_lds[AE_P];

    const float* tb = tags + (size_t)b * (size_t)N * AE_D;
    const int*   kb = kps  + (size_t)b * AE_P * AE_K * 2;

    // ---- Phase 1: cooperative gather of all (p,k) tags into LDS ----
    for (int i = tid; i < AE_P * AE_K; i += 64) {
        const int idx = kb[2 * i + 0];
        const int vis = kb[2 * i + 1];
        const float4 t = *reinterpret_cast<const float4*>(tb + (size_t)idx * AE_D);
        const int p = i / AE_K, k = i % AE_K;
        t_lds[p][k][0] = t.x;
        t_lds[p][k][1] = t.y;
        t_lds[p][k][2] = t.z;
        t_lds[p][k][3] = t.w;
        m_lds[p][k]    = (vis > 0) ? 1.0f : 0.0f;
    }
    __syncthreads();

    // ---- Phase 2: per-person mean + pull term (lane p handles person p) ----
    if (tid < AE_P) {
        float cnt = 0.0f, s0 = 0.0f, s1 = 0.0f, s2 = 0.0f, s3 = 0.0f;
        for (int k = 0; k < AE_K; ++k) {
            const float m = m_lds[tid][k];
            cnt += m;
            s0 += m * t_lds[tid][k][0];
            s1 += m * t_lds[tid][k][1];
            s2 += m * t_lds[tid][k][2];
            s3 += m * t_lds[tid][k][3];
        }
        const float safe = fmaxf(cnt, 1.0f);
        const float mu0 = s0 / safe, mu1 = s1 / safe, mu2 = s2 / safe, mu3 = s3 / safe;
        mean_lds[tid][0] = mu0;
        mean_lds[tid][1] = mu1;
        mean_lds[tid][2] = mu2;
        mean_lds[tid][3] = mu3;
        valid_lds[tid] = (cnt > 0.0f) ? 1.0f : 0.0f;

        float pull = 0.0f;
        for (int k = 0; k < AE_K; ++k) {
            const float d0 = t_lds[tid][k][0] - mu0;
            const float d1 = t_lds[tid][k][1] - mu1;
            const float d2 = t_lds[tid][k][2] - mu2;
            const float d3 = t_lds[tid][k][3] - mu3;
            pull += m_lds[tid][k] * (d0*d0 + d1*d1 + d2*d2 + d3*d3);
        }
        pull_lds[tid] = pull / safe;   // == 0 when cnt==0 (all m are 0)
    }
    __syncthreads();

    // ---- Phase 3: pairwise push over upper triangle, wave reduce ----
    float push = 0.0f;
    for (int i = tid; i < AE_P * AE_P; i += 64) {
        const int pi = i / AE_P, pj = i % AE_P;
        if (pi < pj && valid_lds[pi] > 0.0f && valid_lds[pj] > 0.0f) {
            const float d0 = mean_lds[pi][0] - mean_lds[pj][0];
            const float d1 = mean_lds[pi][1] - mean_lds[pj][1];
            const float d2 = mean_lds[pi][2] - mean_lds[pj][2];
            const float d3 = mean_lds[pi][3] - mean_lds[pj][3];
            const float diff = d0*d0 + d1*d1 + d2*d2 + d3*d3;
            if (diff != 0.0f) push += expf(-diff);
        }
    }

    float pull = (tid < AE_P) ? pull_lds[tid] * valid_lds[tid] : 0.0f;
    float nval = (tid < AE_P) ? valid_lds[tid] : 0.0f;

    #pragma unroll
    for (int off = 32; off > 0; off >>= 1) {
        push += __shfl_down(push, off, 64);
        pull += __shfl_down(pull, off, 64);
        nval += __shfl_down(nval, off, 64);
    }

    if (tid == 0) {
        const float n = nval;
        out[2 * b + 0] = push / ((n - 1.0f) * n + AE_EPS);
        out[2 * b + 1] = pull / (n + AE_EPS);
    }
}

extern "C" void kernel_launch(void* const* d_in, const int* in_sizes, int n_in,
                              void* d_out, int out_size, void* d_ws, size_t ws_size,
                              hipStream_t stream)
{
    const float* tags = (const float*)d_in[0];   // (B, N, D) float32
    const int*   kps  = (const int*)d_in[1];     // (B, P, K, 2) int (narrowed from int64)
    float* out = (float*)d_out;                  // (B, 2) float32

    const int B = out_size / 2;                          // 32
    const int N = (int)(in_sizes[0] / ((size_t)B * AE_D)); // 278528

    aeloss_kernel<<<B, 64, 0, stream>>>(tags, kps, out, N);
}

// Round 2
// 9.426 us; speedup vs baseline: 1.3493x; 1.3493x over previous
//
#include <hip/hip_runtime.h>

#define AE_EPS 1e-6f

// Problem-structure constants (from reference setup_inputs):
//   B=32 images, P=30 persons, K=17 keypoints, D=4 tag dims, N=17*128*128.
constexpr int AE_P = 30;
constexpr int AE_K = 17;
constexpr int AE_D = 4;
constexpr int AE_PK = AE_P * AE_K;   // 510
constexpr int AE_THREADS = 512;      // 8 waves: one thread per (p,k)

__global__ __launch_bounds__(AE_THREADS)
void aeloss_kernel(const float* __restrict__ tags,
                   const int*  __restrict__ kps,
                   float* __restrict__ out,
                   int N)
{
    const int b   = blockIdx.x;
    const int tid = threadIdx.x;

    __shared__ float t_lds[AE_P][AE_K][AE_D];   // gathered tags
    __shared__ float m_lds[AE_P][AE_K];         // visibility mask (0/1)
    __shared__ float mean_lds[AE_P][AE_D];
    __shared__ float pull_lds[AE_P];
    __shared__ float valid_lds[AE_P];
    __shared__ float part_lds[AE_THREADS / 64][3];  // per-wave {push,pull,n}

    const float* tb = tags + (size_t)b * (size_t)N * AE_D;
    const int*   kb = kps  + (size_t)b * AE_PK * 2;

    // ---- Phase 1: one thread per (p,k); all 510 gathers in flight at once ----
    if (tid < AE_PK) {
        const int idx = kb[2 * tid + 0];
        const int vis = kb[2 * tid + 1];
        const float4 t = *reinterpret_cast<const float4*>(tb + (size_t)idx * AE_D);
        const int p = tid / AE_K, k = tid % AE_K;
        t_lds[p][k][0] = t.x;
        t_lds[p][k][1] = t.y;
        t_lds[p][k][2] = t.z;
        t_lds[p][k][3] = t.w;
        m_lds[p][k]    = (vis > 0) ? 1.0f : 0.0f;
    }
    __syncthreads();

    // ---- Phase 2: per-person mean + pull (thread p owns person p) ----
    if (tid < AE_P) {
        float cnt = 0.0f, s0 = 0.0f, s1 = 0.0f, s2 = 0.0f, s3 = 0.0f;
        #pragma unroll
        for (int k = 0; k < AE_K; ++k) {
            const float m = m_lds[tid][k];
            cnt += m;
            s0 += m * t_lds[tid][k][0];
            s1 += m * t_lds[tid][k][1];
            s2 += m * t_lds[tid][k][2];
            s3 += m * t_lds[tid][k][3];
        }
        const float safe = fmaxf(cnt, 1.0f);
        const float mu0 = s0 / safe, mu1 = s1 / safe, mu2 = s2 / safe, mu3 = s3 / safe;
        mean_lds[tid][0] = mu0;
        mean_lds[tid][1] = mu1;
        mean_lds[tid][2] = mu2;
        mean_lds[tid][3] = mu3;
        valid_lds[tid] = (cnt > 0.0f) ? 1.0f : 0.0f;

        float pull = 0.0f;
        #pragma unroll
        for (int k = 0; k < AE_K; ++k) {
            const float d0 = t_lds[tid][k][0] - mu0;
            const float d1 = t_lds[tid][k][1] - mu1;
            const float d2 = t_lds[tid][k][2] - mu2;
            const float d3 = t_lds[tid][k][3] - mu3;
            pull += m_lds[tid][k] * (d0*d0 + d1*d1 + d2*d2 + d3*d3);
        }
        pull_lds[tid] = (pull / safe) * valid_lds[tid];
    }
    __syncthreads();

    // ---- Phase 3: pairwise push; <=2 pairs per thread ----
    float push = 0.0f;
    #pragma unroll
    for (int i = tid; i < AE_P * AE_P; i += AE_THREADS) {
        const int pi = i / AE_P, pj = i % AE_P;
        if (pi < pj && valid_lds[pi] > 0.0f && valid_lds[pj] > 0.0f) {
            const float d0 = mean_lds[pi][0] - mean_lds[pj][0];
            const float d1 = mean_lds[pi][1] - mean_lds[pj][1];
            const float d2 = mean_lds[pi][2] - mean_lds[pj][2];
            const float d3 = mean_lds[pi][3] - mean_lds[pj][3];
            const float diff = d0*d0 + d1*d1 + d2*d2 + d3*d3;
            if (diff != 0.0f) push += expf(-diff);
        }
    }

    float pull = (tid < AE_P) ? pull_lds[tid] : 0.0f;
    float nval = (tid < AE_P) ? valid_lds[tid] : 0.0f;

    // per-wave reduce (width 64)
    #pragma unroll
    for (int off = 32; off > 0; off >>= 1) {
        push += __shfl_down(push, off, 64);
        pull += __shfl_down(pull, off, 64);
        nval += __shfl_down(nval, off, 64);
    }
    const int wave = tid >> 6;
    if ((tid & 63) == 0) {
        part_lds[wave][0] = push;
        part_lds[wave][1] = pull;
        part_lds[wave][2] = nval;
    }
    __syncthreads();

    if (tid == 0) {
        float tpush = 0.0f, tpull = 0.0f, tn = 0.0f;
        #pragma unroll
        for (int w = 0; w < AE_THREADS / 64; ++w) {
            tpush += part_lds[w][0];
            tpull += part_lds[w][1];
            tn    += part_lds[w][2];
        }
        out[2 * b + 0] = tpush / ((tn - 1.0f) * tn + AE_EPS);
        out[2 * b + 1] = tpull / (tn + AE_EPS);
    }
}

extern "C" void kernel_launch(void* const* d_in, const int* in_sizes, int n_in,
                              void* d_out, int out_size, void* d_ws, size_t ws_size,
                              hipStream_t stream)
{
    const float* tags = (const float*)d_in[0];   // (B, N, D) float32
    const int*   kps  = (const int*)d_in[1];     // (B, P, K, 2) int (narrowed from int64)
    float* out = (float*)d_out;                  // (B, 2) float32

    const int B = out_size / 2;                            // 32
    const int N = (int)(in_sizes[0] / ((size_t)B * AE_D)); // 278528

    aeloss_kernel<<<B, AE_THREADS, 0, stream>>>(tags, kps, out, N);
}